// Round 1
// baseline (1305.211 us; speedup 1.0000x reference)
//
#include <hip/hip_runtime.h>

typedef __attribute__((ext_vector_type(8))) short s16x8;
typedef __attribute__((ext_vector_type(8))) unsigned short u16x8;
typedef __attribute__((ext_vector_type(4))) float f32x4;
typedef unsigned short u16;

// ---------- bf16 split helpers (RNE) ----------
__device__ __forceinline__ u16 f2bf(float x) {
  unsigned u = __builtin_bit_cast(unsigned, x);
  u = u + 0x7fffu + ((u >> 16) & 1u);
  return (u16)(u >> 16);
}
__device__ __forceinline__ float bf2f(u16 h) {
  return __builtin_bit_cast(float, (unsigned)h << 16);
}
__device__ __forceinline__ void split_bf(float x, u16 &h, u16 &l) {
  h = f2bf(x);
  l = f2bf(x - bf2f(h));
}

// ---------- transpose + split: mb [b][S=2048][D=1024] f32 -> mbT hi/lo [b][D][S] bf16 ----------
__global__ __launch_bounds__(256) void transpose_split_k(
    const float* __restrict__ in, u16* __restrict__ oh, u16* __restrict__ ol) {
  __shared__ float tile[64][65];
  const int b = blockIdx.z;
  const int s0 = blockIdx.x * 64, d0 = blockIdx.y * 64;
  const float* pin = in + (long)b * 2048 * 1024;
  const int t = threadIdx.x;
#pragma unroll
  for (int i = 0; i < 16; ++i) {
    const int idx = i * 256 + t;
    const int r = idx >> 6, c = idx & 63;
    tile[r][c] = pin[(long)(s0 + r) * 1024 + d0 + c];
  }
  __syncthreads();
  u16* poh = oh + (long)b * 1024 * 2048;
  u16* pol = ol + (long)b * 1024 * 2048;
#pragma unroll
  for (int i = 0; i < 16; ++i) {
    const int idx = i * 256 + t;
    const int r = idx >> 6, c = idx & 63;   // r: d, c: s
    u16 h, l; split_bf(tile[c][r], h, l);
    const long o = (long)(d0 + r) * 2048 + s0 + c;
    poh[o] = h; pol[o] = l;
  }
}

// ---------- contiguous split: f32 -> hi/lo bf16 ----------
__global__ __launch_bounds__(256) void split_copy_k(
    const float* __restrict__ in, u16* __restrict__ oh, u16* __restrict__ ol, long n) {
  const long i = (long)blockIdx.x * 256 + threadIdx.x;
  if (i < n) { u16 h, l; split_bf(in[i], h, l); oh[i] = h; ol[i] = l; }
}

// ---------- masked softmax over S=2048, writes P f32 to out [T,B,S] and hi/lo packed in place ----------
__global__ __launch_bounds__(256) void softmax_k(
    float* __restrict__ alignBuf, const int* __restrict__ lens, float* __restrict__ outP) {
  const int row = blockIdx.x;          // b*1024 + t
  const int b = row >> 10;
  const int tt = row & 1023;
  const int len = lens[b];
  float* arow = alignBuf + (long)row * 2048;
  const int t = threadIdx.x;
  const int lane = t & 63, wv = t >> 6;
  float v[8];
  float mx = -3.0e38f;
#pragma unroll
  for (int j = 0; j < 8; ++j) {
    const int s = j * 256 + t;
    float x = arow[s];
    x = (s < len) ? x : -1.0e9f;
    v[j] = x;
    mx = fmaxf(mx, x);
  }
#pragma unroll
  for (int off = 32; off; off >>= 1) mx = fmaxf(mx, __shfl_xor(mx, off));
  __shared__ float redm[4], reds[4];
  if (lane == 0) redm[wv] = mx;
  __syncthreads();
  mx = fmaxf(fmaxf(redm[0], redm[1]), fmaxf(redm[2], redm[3]));
  float e[8]; float sum = 0.f;
#pragma unroll
  for (int j = 0; j < 8; ++j) { e[j] = __expf(v[j] - mx); sum += e[j]; }
#pragma unroll
  for (int off = 32; off; off >>= 1) sum += __shfl_xor(sum, off);
  if (lane == 0) reds[wv] = sum;
  __syncthreads();   // also fences: all reads of arow are done before any in-place write below
  sum = reds[0] + reds[1] + reds[2] + reds[3];
  const float inv = 1.0f / sum;
  u16* ph = (u16*)arow;          // 2048 hi bf16 (bytes [0,4096))
  u16* pl = ph + 2048;           // 2048 lo bf16 (bytes [4096,8192))
  float* orow = outP + ((long)tt * 16 + b) * 2048;
#pragma unroll
  for (int j = 0; j < 8; ++j) {
    const int s = j * 256 + t;
    const float pv = e[j] * inv;
    orow[s] = pv;
    u16 h, l; split_bf(pv, h, l);
    ph[s] = h; pl[s] = l;
  }
}

// ---------- split-bf16 compensated GEMM, BT layout (both operands K-contiguous) ----------
// C[m,n] = sum_k A[m,k]*B[n,k], computed as (Ah+Al)(Bh+Bl) dropping Al*Bl.
// A from hi/lo bf16 arrays, with optional second array pair for k >= kSplitA (concat trick).
// B either from hi/lo bf16 arrays (BF32=0) or split on the fly from f32 (BF32=1).
// EP: 0 = f32 C, 1 = split hi/lo C, 2 = tanh + [T,B,D] transposed f32 store.
template<int EP, int BF32>
__global__ __launch_bounds__(256, 2) void gemm_split(
    const u16* __restrict__ Ah, const u16* __restrict__ Al,
    const u16* __restrict__ Ah2, const u16* __restrict__ Al2,
    int kSplitA, int lda, long sA,
    const u16* __restrict__ Bh, const u16* __restrict__ Bl,
    const float* __restrict__ Bf, int ldb, long sB,
    int K,
    float* __restrict__ Cf, u16* __restrict__ Ch, u16* __restrict__ Cl,
    int ldc, long sC) {
  __shared__ u16 ldsA[2][4096];   // [hi/lo][ [kc(4)][row(128)][8] ]
  __shared__ u16 ldsB[2][4096];

  const int t = threadIdx.x;
  const int lane = t & 63;
  const int wv = t >> 6;
  const int wm = wv >> 1, wn = wv & 1;
  const long m0 = (long)blockIdx.y * 128;
  const long n0 = (long)blockIdx.x * 128;
  const int bz = blockIdx.z;

  const u16* pAh = Ah + (long)bz * sA;
  const u16* pAl = Al + (long)bz * sA;
  const u16* pAh2 = Ah2 + (long)bz * sA;
  const u16* pAl2 = Al2 + (long)bz * sA;
  const u16* pBh = Bh + (long)bz * sB;
  const u16* pBl = Bl + (long)bz * sB;
  const float* pBf = Bf + (long)bz * sB;

  f32x4 acc[4][4];
#pragma unroll
  for (int i = 0; i < 4; ++i)
#pragma unroll
    for (int j = 0; j < 4; ++j) acc[i][j] = 0.0f;

  const int lk = lane >> 4;
  const int lr = lane & 15;
  const int fragBase = lk * 1024;   // element offset of this lane-group's k-chunk

  for (int k0 = 0; k0 < K; k0 += 32) {
    __syncthreads();
    // stage 128x32 hi/lo tiles for A and B, layout [kc][row][8]
#pragma unroll
    for (int j = 0; j < 2; ++j) {
      const int c = j * 256 + t;
      const int kc = c >> 7, r = c & 127;
      const int k = k0 + kc * 8;
      const u16 *aH, *aL; int ka;
      if (k < kSplitA) { aH = pAh;  aL = pAl;  ka = k; }
      else             { aH = pAh2; aL = pAl2; ka = k - kSplitA; }
      const long aoff = (m0 + r) * (long)lda + ka;
      *(u16x8*)&ldsA[0][c * 8] = *(const u16x8*)(aH + aoff);
      *(u16x8*)&ldsA[1][c * 8] = *(const u16x8*)(aL + aoff);
      if constexpr (BF32 != 0) {
        const float* s = pBf + (n0 + r) * (long)ldb + k;
        u16x8 bh, bl;
#pragma unroll
        for (int e = 0; e < 8; ++e) { u16 hh, ll; split_bf(s[e], hh, ll); bh[e] = hh; bl[e] = ll; }
        *(u16x8*)&ldsB[0][c * 8] = bh;
        *(u16x8*)&ldsB[1][c * 8] = bl;
      } else {
        const long boff = (n0 + r) * (long)ldb + k;
        *(u16x8*)&ldsB[0][c * 8] = *(const u16x8*)(pBh + boff);
        *(u16x8*)&ldsB[1][c * 8] = *(const u16x8*)(pBl + boff);
      }
    }
    __syncthreads();

    s16x8 ah[4], al[4], bh[4], bl[4];
#pragma unroll
    for (int f = 0; f < 4; ++f) {
      const int ra = wm * 64 + f * 16 + lr;
      const int rb = wn * 64 + f * 16 + lr;
      ah[f] = *(const s16x8*)&ldsA[0][fragBase + ra * 8];
      al[f] = *(const s16x8*)&ldsA[1][fragBase + ra * 8];
      bh[f] = *(const s16x8*)&ldsB[0][fragBase + rb * 8];
      bl[f] = *(const s16x8*)&ldsB[1][fragBase + rb * 8];
    }
#pragma unroll
    for (int i = 0; i < 4; ++i)
#pragma unroll
      for (int j = 0; j < 4; ++j) {
        acc[i][j] = __builtin_amdgcn_mfma_f32_16x16x32_bf16(ah[i], bh[j], acc[i][j], 0, 0, 0);
        acc[i][j] = __builtin_amdgcn_mfma_f32_16x16x32_bf16(ah[i], bl[j], acc[i][j], 0, 0, 0);
        acc[i][j] = __builtin_amdgcn_mfma_f32_16x16x32_bf16(al[i], bh[j], acc[i][j], 0, 0, 0);
      }
  }

  // epilogue; C/D frag: col = lane&15, row = (lane>>4)*4 + reg  [m89-verified]
#pragma unroll
  for (int fm = 0; fm < 4; ++fm)
#pragma unroll
    for (int fn = 0; fn < 4; ++fn)
#pragma unroll
      for (int r = 0; r < 4; ++r) {
        const long row = m0 + wm * 64 + fm * 16 + (lane >> 4) * 4 + r;
        const long col = n0 + wn * 64 + fn * 16 + lr;
        const float v = acc[fm][fn][r];
        if constexpr (EP == 0) {
          Cf[(long)bz * sC + row * ldc + col] = v;
        } else if constexpr (EP == 1) {
          u16 h, l; split_bf(v, h, l);
          const long o = (long)bz * sC + row * ldc + col;
          Ch[o] = h; Cl[o] = l;
        } else {
          const long bb = row >> 10;       // batch (T=1024)
          const long tt = row & 1023;      // t
          Cf[(tt * 16 + bb) * (long)ldc + col] = tanhf(v);
        }
      }
}

extern "C" void kernel_launch(void* const* d_in, const int* in_sizes, int n_in,
                              void* d_out, int out_size, void* d_ws, size_t ws_size,
                              hipStream_t stream) {
  (void)in_sizes; (void)n_in; (void)out_size; (void)ws_size;
  const float* src = (const float*)d_in[0];   // [16,1024,1024]
  const float* mb  = (const float*)d_in[1];   // [16,2048,1024]
  const int*   lens= (const int*)d_in[2];     // [16]
  const float* Wi  = (const float*)d_in[3];   // [1024,1024]
  const float* Wo  = (const float*)d_in[4];   // [1024,2048]
  float* out = (float*)d_out;                 // [T,B,D] f32 then [T,B,S] f32

  // workspace layout (403 MB total)
  char* p = (char*)d_ws;
  u16* mbT_hi  = (u16*)p; p += 67108864;   // [b][D][S]
  u16* mbT_lo  = (u16*)p; p += 67108864;
  u16* srcU_hi = (u16*)p; p += 33554432;   // [16384][1024]
  u16* srcU_lo = (u16*)p; p += 33554432;
  u16* htc_hi  = (u16*)p; p += 33554432;   // h_t, later c  [16384][1024]
  u16* htc_lo  = (u16*)p; p += 33554432;
  float* alignBuf = (float*)p;             // [16][1024][2048] f32, reused for P hi/lo

  dim3 blk(256);
  transpose_split_k<<<dim3(32, 16, 16), blk, 0, stream>>>(mb, mbT_hi, mbT_lo);
  split_copy_k<<<dim3(65536), blk, 0, stream>>>(src, srcU_hi, srcU_lo, 16777216L);

  // GEMM1: h_t = src @ Wi^T   (M=16384,N=1024,K=1024), B split on the fly from f32
  gemm_split<1, 1><<<dim3(8, 128, 1), blk, 0, stream>>>(
      srcU_hi, srcU_lo, srcU_hi, srcU_lo, 1024, 1024, 0L,
      nullptr, nullptr, Wi, 1024, 0L, 1024,
      nullptr, htc_hi, htc_lo, 1024, 0L);

  // GEMM2: align[b] = h_t[b] @ mb[b]^T  (M=1024,N=2048,K=1024) x16
  gemm_split<0, 1><<<dim3(16, 8, 16), blk, 0, stream>>>(
      htc_hi, htc_lo, htc_hi, htc_lo, 1024, 1024, 1048576L,
      nullptr, nullptr, mb, 1024, 2097152L, 1024,
      alignBuf, nullptr, nullptr, 2048, 2097152L);

  // masked softmax; P f32 -> d_out[1], P hi/lo packed in place over alignBuf
  softmax_k<<<dim3(16384), blk, 0, stream>>>(alignBuf, lens, out + 16777216L);

  // GEMM3: c[b] = P[b] @ mbT[b]^T (BT over s)  (M=1024,N=1024,K=2048) x16, C -> htc (aliases dead h_t)
  gemm_split<1, 0><<<dim3(8, 8, 16), blk, 0, stream>>>(
      (const u16*)alignBuf, (const u16*)alignBuf + 2048,
      (const u16*)alignBuf, (const u16*)alignBuf + 2048, 2048, 4096, 4194304L,
      mbT_hi, mbT_lo, nullptr, 2048, 2097152L, 2048,
      nullptr, htc_hi, htc_lo, 1024, 1048576L);

  // GEMM4: attn = tanh([c,src] @ Wo^T)  (M=16384,N=1024,K=2048), A switches arrays at k=1024
  gemm_split<2, 1><<<dim3(8, 128, 1), blk, 0, stream>>>(
      htc_hi, htc_lo, srcU_hi, srcU_lo, 1024, 1024, 0L,
      nullptr, nullptr, Wo, 2048, 0L, 2048,
      out, nullptr, nullptr, 1024, 0L);
}